// Round 5
// baseline (5362.595 us; speedup 1.0000x reference)
//
#include <hip/hip_runtime.h>
#include <math.h>

#define Hh  8
#define Dd  512
#define SUB 256          // D/2
#define Nk  1024         // num_subkeys
#define TK  32           // top_k
#define NT  256
#define W_ELEMS (65536 * 32)

// Arithmetic contract (validated round 4): per (row,key) score is a single
// accumulator walked d=0..255 ascending with fused fmaf; all rankings use
// stable lowest-index tie-break; product scores are single __fadd_rn.

__global__ __launch_bounds__(NT, 2)
void pk_kernel(const float* __restrict__ query,
               const float* __restrict__ keyl,
               const float* __restrict__ keyr,
               float* __restrict__ out)
{
    // key tile: 64 rows x 256 dims, stored as 16B cells [j][row^swz] (64 KB)
    __shared__ float4 ktile[4096];
    __shared__ float topv[4][2][8][TK];   // 8 KB
    __shared__ int   topi[4][2][8][TK];   // 8 KB

    const int t    = threadIdx.x;
    const int lane = t & 63;
    const int wv   = t >> 6;
    // wave id, forced wave-uniform so q addressing uses the scalar pipe
    const int W    = __builtin_amdgcn_readfirstlane(blockIdx.x * 4 + wv);
    const int h    = W >> 10;             // 256 consecutive blocks share h -> L2 key locality
    const int bc0  = (W & 1023) * 8;      // 8 rows (b,c) per wave, fixed h

    float acc[8][16];                     // acc[row][ig] = score(row, key ig*64+lane)

    for (int side = 0; side < 2; ++side) {
        const float* kbase = (side == 0 ? keyl : keyr) + (size_t)h * Nk * SUB;
        const float4* qp[8];
        #pragma unroll
        for (int r = 0; r < 8; ++r)
            qp[r] = (const float4*)(query + ((size_t)(bc0 + r) * Hh + h) * Dd + side * SUB);

        #pragma unroll
        for (int r = 0; r < 8; ++r)
            #pragma unroll
            for (int i = 0; i < 16; ++i) acc[r][i] = 0.0f;

        for (int ig = 0; ig < 16; ++ig) {
            __syncthreads();              // previous tile fully consumed
            // ---- stage 64-row key tile, coalesced global -> swizzled LDS ----
            {
                const float4* gk = (const float4*)(kbase + (size_t)ig * 64 * SUB);
                #pragma unroll
                for (int c = 0; c < 16; ++c) {
                    float4 v = gk[c * 256 + t];
                    int r_g = 4 * c + (t >> 6);       // row in tile
                    int j_g = t & 63;                 // dim chunk
                    ktile[j_g * 64 + (r_g ^ (j_g & 7))] = v;
                }
            }
            __syncthreads();
            // ---- compute: lane owns key row ig*64+lane ----
            for (int j = 0; j < 64; ++j) {
                float4 kv = ktile[j * 64 + (lane ^ (j & 7))];
                #pragma unroll
                for (int r = 0; r < 8; ++r) {
                    float4 qv = qp[r][j];             // wave-uniform -> s_load
                    acc[r][ig] = fmaf(qv.x, kv.x, acc[r][ig]);
                    acc[r][ig] = fmaf(qv.y, kv.y, acc[r][ig]);
                    acc[r][ig] = fmaf(qv.z, kv.z, acc[r][ig]);
                    acc[r][ig] = fmaf(qv.w, kv.w, acc[r][ig]);
                }
            }
        }

        // ---- phase 2: in-register top-32 per row (stable lowest-index) ----
        #pragma unroll
        for (int r = 0; r < 8; ++r) {
            for (int it = 0; it < TK; ++it) {
                float bv = acc[r][0]; int bp = lane;
                #pragma unroll
                for (int i = 1; i < 16; ++i)
                    if (acc[r][i] > bv) { bv = acc[r][i]; bp = lane + 64 * i; }
                #pragma unroll
                for (int m = 1; m < 64; m <<= 1) {
                    float ov = __shfl_xor(bv, m, 64);
                    int   op = __shfl_xor(bp, m, 64);
                    if (ov > bv || (ov == bv && op < bp)) { bv = ov; bp = op; }
                }
                if (lane == it) { topv[wv][side][r][it] = bv; topi[wv][side][r][it] = bp; }
                if (lane == (bp & 63)) acc[r][bp >> 6] = -INFINITY;
            }
        }
        // no barrier: topv/topi are written and read by the same wave
    }

    // ---- phase 3: 32x32 products, top-32, softmax, store ----
    #pragma unroll
    for (int r = 0; r < 8; ++r) {
        float v[16];
        #pragma unroll
        for (int i = 0; i < 16; ++i) {
            int pos = lane + 64 * i;                  // pos = a*32 + b
            v[i] = __fadd_rn(topv[wv][0][r][pos >> 5], topv[wv][1][r][pos & 31]);
        }
        float m0 = 0.0f, wvv = 0.0f; int wp = 0;
        for (int it = 0; it < TK; ++it) {
            float bv = v[0]; int bp = lane;
            #pragma unroll
            for (int i = 1; i < 16; ++i)
                if (v[i] > bv) { bv = v[i]; bp = lane + 64 * i; }
            #pragma unroll
            for (int m = 1; m < 64; m <<= 1) {
                float ov = __shfl_xor(bv, m, 64);
                int   op = __shfl_xor(bp, m, 64);
                if (ov > bv || (ov == bv && op < bp)) { bv = ov; bp = op; }
            }
            if (it == 0) m0 = bv;                     // rank 0 = max
            if (lane == it) { wvv = bv; wp = bp; }
            if (lane == (bp & 63)) v[bp >> 6] = -INFINITY;
        }
        float e = (lane < TK) ? expf(wvv - m0) : 0.0f;
        float s = e;
        #pragma unroll
        for (int m = 1; m < 64; m <<= 1) s += __shfl_xor(s, m, 64);
        if (lane < TK) {
            const int bc = bc0 + r;
            const size_t base = ((size_t)bc * Hh + h) * TK;
            const int a = wp >> 5;
            // reference quirk: product_indices[a*32+b] = l[a]*N + r[a]
            const int fl = topi[wv][0][r][a] * Nk + topi[wv][1][r][a];
            out[base + lane] = e / s;
            out[(size_t)W_ELEMS + base + lane] = (float)fl;
        }
    }
}

extern "C" void kernel_launch(void* const* d_in, const int* in_sizes, int n_in,
                              void* d_out, int out_size, void* d_ws, size_t ws_size,
                              hipStream_t stream)
{
    const float* query = (const float*)d_in[0];
    const float* keyl  = (const float*)d_in[1];
    const float* keyr  = (const float*)d_in[2];
    float* out = (float*)d_out;
    pk_kernel<<<dim3(2048), dim3(NT), 0, stream>>>(query, keyl, keyr, out);
}